// Round 1
// baseline (180.653 us; speedup 1.0000x reference)
//
#include <hip/hip_runtime.h>

#define N_NODES 20000
#define N_EDGES 160000
#define N_PAIRS 50000
// F_IN = CHANNELS = 32, EDGE_DIM = 8

// W2 layout: [i=0..31][c=0..319]
//   c in [0,256):  d = c>>5, o = c&31  -> knw[d*1024 + i*32 + o]
//   c in [256,288): o = c-256          -> knb[i*32 + o]
//   c in [288,320): o = c-288          -> root[i*32 + o]
__global__ void build_w2(const float* __restrict__ knw, const float* __restrict__ knb,
                         const float* __restrict__ root, float* __restrict__ w2) {
    int t = blockIdx.x * blockDim.x + threadIdx.x;
    if (t >= 32 * 320) return;
    int i = t / 320, c = t % 320;
    float v;
    if (c < 256) { int d = c >> 5, o = c & 31; v = knw[d * 1024 + i * 32 + o]; }
    else if (c < 288) { v = knb[i * 32 + (c - 256)]; }
    else { v = root[i * 32 + (c - 288)]; }
    w2[i * 320 + c] = v;
}

// Y[n][c] = sum_i X[n][i] * W2[i][c]   (20000x32 @ 32x320)
__global__ void node_gemm(const float* __restrict__ X, const float* __restrict__ w2,
                          float* __restrict__ Y) {
    int t = blockIdx.x * blockDim.x + threadIdx.x;
    if (t >= N_NODES * 320) return;
    int n = t / 320, c = t % 320;
    const float* xr = X + n * 32;
    float acc = 0.f;
#pragma unroll
    for (int i = 0; i < 32; ++i) acc += xr[i] * w2[i * 320 + c];
    Y[t] = acc;
}

// msg[e][o] = Y[src][256+o] + sum_d e[e][d] * Y[src][d*32+o];  atomicAdd into agg[tgt][o]
__global__ void edge_msg(const float* __restrict__ Y, const float* __restrict__ E,
                         const int* __restrict__ ei, float* __restrict__ agg) {
    int t = blockIdx.x * blockDim.x + threadIdx.x;
    if (t >= N_EDGES * 32) return;
    int eidx = t >> 5, o = t & 31;
    int src = ei[2 * eidx];
    int tgt = ei[2 * eidx + 1];
    const float* y = Y + src * 320;
    const float* ee = E + eidx * 8;
    float m = y[256 + o];
#pragma unroll
    for (int d = 0; d < 8; ++d) m += ee[d] * y[d * 32 + o];
    atomicAdd(&agg[tgt * 32 + o], m);
}

// H[n][o] = relu(agg[n][o] + Y[n][288+o] + bias[o])
__global__ void node_post(const float* __restrict__ agg, const float* __restrict__ Y,
                          const float* __restrict__ bias, float* __restrict__ H) {
    int t = blockIdx.x * blockDim.x + threadIdx.x;
    if (t >= N_NODES * 32) return;
    int n = t >> 5, o = t & 31;
    float v = agg[t] + Y[n * 320 + 288 + o] + bias[o];
    H[t] = v > 0.f ? v : 0.f;
}

// util[n] = db + sum_o H[n][o]*dw[o]
__global__ void util_kernel(const float* __restrict__ H, const float* __restrict__ dw,
                            const float* __restrict__ db, float* __restrict__ util) {
    int n = blockIdx.x * blockDim.x + threadIdx.x;
    if (n >= N_NODES) return;
    float acc = db[0];
#pragma unroll
    for (int o = 0; o < 32; ++o) acc += H[n * 32 + o] * dw[o];
    util[n] = acc;
}

// out[p] = util[idx_b[p]] - util[idx_a[p]]
__global__ void pair_kernel(const float* __restrict__ util, const int* __restrict__ ia,
                            const int* __restrict__ ib, float* __restrict__ out) {
    int p = blockIdx.x * blockDim.x + threadIdx.x;
    if (p >= N_PAIRS) return;
    out[p] = util[ib[p]] - util[ia[p]];
}

extern "C" void kernel_launch(void* const* d_in, const int* in_sizes, int n_in,
                              void* d_out, int out_size, void* d_ws, size_t ws_size,
                              hipStream_t stream) {
    const float* x     = (const float*)d_in[0];
    const float* e     = (const float*)d_in[1];
    const float* knw1  = (const float*)d_in[2];
    const float* knb1  = (const float*)d_in[3];
    const float* root1 = (const float*)d_in[4];
    const float* bias1 = (const float*)d_in[5];
    const float* knw2  = (const float*)d_in[6];
    const float* knb2  = (const float*)d_in[7];
    const float* root2 = (const float*)d_in[8];
    const float* bias2 = (const float*)d_in[9];
    const float* dw    = (const float*)d_in[10];
    const float* db    = (const float*)d_in[11];
    const int*   ei    = (const int*)d_in[12];
    const int*   ia    = (const int*)d_in[13];
    const int*   ib    = (const int*)d_in[14];
    float* out = (float*)d_out;

    float* ws  = (float*)d_ws;
    float* Y    = ws;                  // 20000*320 = 6,400,000 floats
    float* agg  = ws + 6400000;        // 640,000 floats
    float* H    = ws + 7040000;        // 640,000 floats
    float* W2   = ws + 7680000;        // 10,240 floats
    float* util = ws + 7690240;        // 20,000 floats

    // ---- layer 1 ----
    build_w2<<<40, 256, 0, stream>>>(knw1, knb1, root1, W2);
    node_gemm<<<(N_NODES * 320) / 256, 256, 0, stream>>>(x, W2, Y);
    hipMemsetAsync(agg, 0, (size_t)N_NODES * 32 * sizeof(float), stream);
    edge_msg<<<(N_EDGES * 32) / 256, 256, 0, stream>>>(Y, e, ei, agg);
    node_post<<<(N_NODES * 32) / 256, 256, 0, stream>>>(agg, Y, bias1, H);

    // ---- layer 2 ----
    build_w2<<<40, 256, 0, stream>>>(knw2, knb2, root2, W2);
    node_gemm<<<(N_NODES * 320) / 256, 256, 0, stream>>>(H, W2, Y);
    hipMemsetAsync(agg, 0, (size_t)N_NODES * 32 * sizeof(float), stream);
    edge_msg<<<(N_EDGES * 32) / 256, 256, 0, stream>>>(Y, e, ei, agg);
    node_post<<<(N_NODES * 32) / 256, 256, 0, stream>>>(agg, Y, bias2, H);

    // ---- readout ----
    util_kernel<<<(N_NODES + 255) / 256, 256, 0, stream>>>(H, dw, db, util);
    pair_kernel<<<(N_PAIRS + 255) / 256, 256, 0, stream>>>(util, ia, ib, out);
}